// Round 4
// baseline (2618.283 us; speedup 1.0000x reference)
//
#include <hip/hip_runtime.h>

// CompetitiveLayer: K = param^2 (4096x4096 f32), 21 fixed-point iterations of
//   AF = AT/(1+K@BF); BF = BT/(1+AF@K)   -> 42 dependent matvec phases,
// then C = K * AF[:,None] * BF[None,:].
//
// R2/R3 post-mortem: k[256] (1 KiB/lane) never became register-resident —
// VGPR_Count pinned at 168 (=512/3, 3-waves/EU default) regardless of
// waves_per_eu attributes; arch-VGPR ceiling is 256/wave, so pressure ~330
// can't fit and the allocator scratch-spilled (WRITE_SIZE 48 MB over C,
// VALUBusy 1.4%, 1.65 ms latency-bound).
//
// R4 fix: 512 blocks x 256 threads, 2 blocks/CU. Each block owns a 256x128
// tile of K; each lane holds 16x8 = 128 floats as 32 float4s (all
// constant-indexed). Pressure ~200 <= 256 arch VGPRs at 2 waves/EU.

constexpr int N      = 4096;
constexpr int NPHASE = 42;
constexpr int NBLK   = 512;

__device__ __forceinline__ float ld_agent(const float* p) {
    return __hip_atomic_load(p, __ATOMIC_RELAXED, __HIP_MEMORY_SCOPE_AGENT);
}
__device__ __forceinline__ void st_agent(float* p, float v) {
    __hip_atomic_store(p, v, __ATOMIC_RELAXED, __HIP_MEMORY_SCOPE_AGENT);
}

__global__ void __launch_bounds__(256)
__attribute__((amdgpu_waves_per_eu(2, 2)))
competitive_persistent(const float* __restrict__ AT, const float* __restrict__ BT,
                       const float* __restrict__ P,  float* __restrict__ C,
                       float* __restrict__ ws)
{
    const int b  = blockIdx.x;       // 0..511
    const int t  = threadIdx.x;      // 0..255
    const int bR = b >> 5, bC = b & 31;      // 16 row-groups x 32 col-groups
    const int R0 = bR << 8;                  // 256 rows per block
    const int C0 = bC << 7;                  // 128 cols per block
    const int rl = t >> 4, cl = t & 15;
    const int row0 = R0 + rl * 16;           // lane: 16 rows
    const int col0 = C0 + cl * 8;            // lane: 8 cols

    unsigned* bar = (unsigned*)(ws + 3 * (size_t)N);   // host-zeroed

    // ---- Load K = param^2 : 32 float4 per lane, constant-indexed ----
    float4 kk[32];
    #pragma unroll
    for (int r = 0; r < 16; ++r) {
        const float4* src = (const float4*)(P + (size_t)(row0 + r) * N + col0);
        float4 v0 = src[0], v1 = src[1];
        kk[2 * r + 0] = make_float4(v0.x * v0.x, v0.y * v0.y, v0.z * v0.z, v0.w * v0.w);
        kk[2 * r + 1] = make_float4(v1.x * v1.x, v1.y * v1.y, v1.z * v1.z, v1.w * v1.w);
    }

    __shared__ __align__(16) float xsh[256];
    __shared__ __align__(16) float red[512];

    // Rotating 3-buffer scratch (each N floats, host-zeroed):
    //   phase ph accumulates into buf[ph%3], reads buf[(ph+2)%3] (== ph-1),
    //   zeroes buf[(ph+1)%3]. Phase 0 reads the zeroed buffer -> BF = BT.
    #pragma unroll 1
    for (int ph = 0; ph < NPHASE; ++ph) {
        float*       D = ws + (size_t)N * (ph % 3);
        const float* S = ws + (size_t)N * ((ph + 2) % 3);
        float*       Z = ws + (size_t)N * ((ph + 1) % 3);
        const bool rowPhase = ((ph & 1) == 0);

        // Stage x-vector slice into LDS (one divide per element).
        if (rowPhase) {
            if (t < 128) {
                const float s = ld_agent(S + C0 + t);
                xsh[t] = BT[C0 + t] / (1.0f + s);
            }
        } else {
            const float s = ld_agent(S + R0 + t);
            xsh[t] = AT[R0 + t] / (1.0f + s);
        }
        // Zero the accumulator of phase ph+1 (its last readers finished
        // before the previous grid barrier).
        if (t < 8) st_agent(Z + b * 8 + t, 0.0f);
        __syncthreads();

        if (rowPhase) {
            // y[i] += sum_j K[i,j]*BF[j] over this lane's 8 cols
            const float4 x0 = ((const float4*)(xsh + cl * 8))[0];
            const float4 x1 = ((const float4*)(xsh + cl * 8))[1];
            float part[16];
            #pragma unroll
            for (int r = 0; r < 16; ++r) {
                const float4 a = kk[2 * r + 0];
                const float4 c = kk[2 * r + 1];
                part[r] = a.x * x0.x + a.y * x0.y + a.z * x0.z + a.w * x0.w
                        + c.x * x1.x + c.y * x1.y + c.z * x1.z + c.w * x1.w;
            }
            // Reduce across the 16 cl-lanes (lane-id bits 0..3).
            #pragma unroll
            for (int off = 1; off < 16; off <<= 1) {
                #pragma unroll
                for (int r = 0; r < 16; ++r)
                    part[r] += __shfl_xor(part[r], off, 64);
            }
            if (cl == 0) {
                #pragma unroll
                for (int r = 0; r < 16; ++r)
                    atomicAdd(D + row0 + r, part[r]);   // 32-way (col-groups)
            }
        } else {
            // y[j] += sum_i AF[i]*K[i,j] over this lane's 16 rows
            float4 acc0 = make_float4(0.f, 0.f, 0.f, 0.f);
            float4 acc1 = make_float4(0.f, 0.f, 0.f, 0.f);
            #pragma unroll
            for (int r = 0; r < 16; ++r) {
                const float a = xsh[rl * 16 + r];
                const float4 k0 = kk[2 * r + 0];
                const float4 k1 = kk[2 * r + 1];
                acc0.x = fmaf(k0.x, a, acc0.x); acc0.y = fmaf(k0.y, a, acc0.y);
                acc0.z = fmaf(k0.z, a, acc0.z); acc0.w = fmaf(k0.w, a, acc0.w);
                acc1.x = fmaf(k1.x, a, acc1.x); acc1.y = fmaf(k1.y, a, acc1.y);
                acc1.z = fmaf(k1.z, a, acc1.z); acc1.w = fmaf(k1.w, a, acc1.w);
            }
            // Reduce across rl bits 0,1 (lane-id bits 4,5) within the wave.
            #pragma unroll
            for (int off = 16; off <= 32; off <<= 1) {
                acc0.x += __shfl_xor(acc0.x, off, 64);
                acc0.y += __shfl_xor(acc0.y, off, 64);
                acc0.z += __shfl_xor(acc0.z, off, 64);
                acc0.w += __shfl_xor(acc0.w, off, 64);
                acc1.x += __shfl_xor(acc1.x, off, 64);
                acc1.y += __shfl_xor(acc1.y, off, 64);
                acc1.z += __shfl_xor(acc1.z, off, 64);
                acc1.w += __shfl_xor(acc1.w, off, 64);
            }
            const int w = t >> 6;                 // wave id 0..3
            if ((t & 63) < 16) {                  // one lane per cl per wave
                ((float4*)(red + w * 128 + cl * 8))[0] = acc0;
                ((float4*)(red + w * 128 + cl * 8))[1] = acc1;
            }
            __syncthreads();
            if (t < 128) {
                const float s4 = red[t] + red[128 + t] + red[256 + t] + red[384 + t];
                atomicAdd(D + C0 + t, s4);        // 16-way (row-groups)
            }
        }

        // ---- Manual grid barrier (monotonic counter, no reset) ----
        __threadfence();
        __syncthreads();
        if (t == 0) {
            __hip_atomic_fetch_add(bar, 1u, __ATOMIC_ACQ_REL,
                                   __HIP_MEMORY_SCOPE_AGENT);
            const unsigned target = (unsigned)(NBLK * (ph + 1));
            while (__hip_atomic_load(bar, __ATOMIC_ACQUIRE,
                                     __HIP_MEMORY_SCOPE_AGENT) < target)
                __builtin_amdgcn_s_sleep(2);
        }
        __syncthreads();
    }

    // ---- Epilogue: C = K * AF[:,None] * BF[None,:] ----
    // Row result of phase 40 -> buf1; col result of phase 41 -> buf2.
    const float* yrow = ws + (size_t)N * 1;
    const float* ycol = ws + (size_t)N * 2;
    xsh[t] = AT[R0 + t] / (1.0f + ld_agent(yrow + R0 + t));       // AF slice
    if (t < 128)
        red[t] = BT[C0 + t] / (1.0f + ld_agent(ycol + C0 + t));   // BF slice
    __syncthreads();

    const float4 b0 = ((const float4*)(red + cl * 8))[0];
    const float4 b1 = ((const float4*)(red + cl * 8))[1];
    #pragma unroll
    for (int r = 0; r < 16; ++r) {
        const float a = xsh[rl * 16 + r];
        const float4 k0 = kk[2 * r + 0];
        const float4 k1 = kk[2 * r + 1];
        float4 o0, o1;
        o0.x = k0.x * a * b0.x; o0.y = k0.y * a * b0.y;
        o0.z = k0.z * a * b0.z; o0.w = k0.w * a * b0.w;
        o1.x = k1.x * a * b1.x; o1.y = k1.y * a * b1.y;
        o1.z = k1.z * a * b1.z; o1.w = k1.w * a * b1.w;
        float4* dst = (float4*)(C + (size_t)(row0 + r) * N + col0);
        dst[0] = o0;
        dst[1] = o1;
    }
}

extern "C" void kernel_launch(void* const* d_in, const int* in_sizes, int n_in,
                              void* d_out, int out_size, void* d_ws, size_t ws_size,
                              hipStream_t stream) {
    const float* AT = (const float*)d_in[0];
    const float* BT = (const float*)d_in[1];
    const float* P  = (const float*)d_in[2];
    float*       C  = (float*)d_out;
    float*       ws = (float*)d_ws;

    // Zero the 3 rotating accumulator buffers + barrier counter.
    hipMemsetAsync(d_ws, 0, (3 * (size_t)N + 16) * sizeof(float), stream);

    competitive_persistent<<<dim3(NBLK), dim3(256), 0, stream>>>(AT, BT, P, C, ws);
}